// Round 1
// 3488.833 us; speedup vs baseline: 3.5227x; 3.5227x over previous
//
#include <hip/hip_runtime.h>
#include <hip/hip_bf16.h>

// GPT fwd: B=4,T=1024,C=1024,H=16,Hd=64,L=4(shared weights),V=32000
// Inputs are FLOAT32 (per reference dtypes); output f32. Internals use bf16 MFMA
// with an f32 residual master. Quirk: k=x@wk(in3), v=x@wq(in4), q=x@wv(in5).

using bf16 = __hip_bfloat16;
typedef __bf16 bf16x8 __attribute__((ext_vector_type(8)));
typedef float f32x4 __attribute__((ext_vector_type(4)));

#define TOK 4096      // B*T
#define C 1024
#define NH 16
#define HD 64
#define TT 1024
#define FF 4096
#define VOC 32000

// ---------------------------------------------------------------- embed
__global__ __launch_bounds__(256) void embed_kernel(
    const int* __restrict__ idx, const float* __restrict__ tok,
    const float* __restrict__ pos, float* __restrict__ xf, bf16* __restrict__ xb)
{
    int i = blockIdx.x * 256 + threadIdx.x;      // over TOK*C
    int t = i >> 10;            // token index 0..4095
    int c = i & 1023;
    int ti = t & 1023;          // position within sequence
    int v = idx[t];
    float val = tok[(size_t)v * C + c] + pos[(size_t)ti * C + c];
    xf[i] = val;
    xb[i] = (bf16)val;
}

// ---------------------------------------------------------------- GEMM
// C[M,N] (+)= A[M,K] @ B.  A is bf16 (internal). B is f32 (original input weight),
// converted to bf16 during LDS staging.
// BT=0: B is KxN row-major. BT=1: B given as B^T (NxK row-major).
// EPI: 0 = store bf16 to Cb; 1 = relu + store bf16; 2 = Xf += acc, Cb=bf16(Xf);
//      3 = store f32 to Cf.
// 64x64 tile, BK=64, 4 waves, mfma_f32_16x16x32_bf16.
template <int BT, int EPI>
__global__ __launch_bounds__(256) void gemm_kernel(
    const bf16* __restrict__ A, const float* __restrict__ B,
    bf16* __restrict__ Cb, float* __restrict__ Cf, float* __restrict__ Xf,
    int M, int N, int K)
{
    __shared__ __align__(16) bf16 As[64][72];
    __shared__ __align__(16) bf16 Bs[64][72];   // stored [n][k]
    const int tid = threadIdx.x;
    const int lane = tid & 63;
    const int wave = tid >> 6;
    const int bm = blockIdx.y * 64;
    const int bn = blockIdx.x * 64;

    f32x4 acc[4] = {};

    const int r_st = tid >> 2;            // staging row 0..63
    const int c_st = (tid & 3) << 4;      // staging col 0,16,32,48

    for (int kc = 0; kc < K; kc += 64) {
        {
            const uint4* src = reinterpret_cast<const uint4*>(A + (size_t)(bm + r_st) * K + kc + c_st);
            uint4* dst = reinterpret_cast<uint4*>(&As[r_st][c_st]);
            dst[0] = src[0];
            dst[1] = src[1];
        }
        if (BT) {  // B^T given (NxK f32)
            const float4* src = reinterpret_cast<const float4*>(B + (size_t)(bn + r_st) * K + kc + c_st);
            #pragma unroll
            for (int j = 0; j < 4; j++) {
                float4 f = src[j];
                int cc = c_st + 4 * j;
                Bs[r_st][cc + 0] = (bf16)f.x;
                Bs[r_st][cc + 1] = (bf16)f.y;
                Bs[r_st][cc + 2] = (bf16)f.z;
                Bs[r_st][cc + 3] = (bf16)f.w;
            }
        } else {   // B is KxN f32: transpose during staging
            #pragma unroll
            for (int i = 0; i < 16; i++) {
                int linear = tid + 256 * i;      // 0..4095
                int k = linear >> 6;
                int n = linear & 63;
                Bs[n][k] = (bf16)B[(size_t)(kc + k) * N + bn + n];
            }
        }
        __syncthreads();

        const int m16 = lane & 15;
        const int koff = (lane >> 4) * 8;
        #pragma unroll
        for (int ks = 0; ks < 64; ks += 32) {
            bf16x8 a = *reinterpret_cast<const bf16x8*>(&As[16 * wave + m16][ks + koff]);
            #pragma unroll
            for (int nt = 0; nt < 4; nt++) {
                bf16x8 b = *reinterpret_cast<const bf16x8*>(&Bs[16 * nt + m16][ks + koff]);
                acc[nt] = __builtin_amdgcn_mfma_f32_16x16x32_bf16(a, b, acc[nt], 0, 0, 0);
            }
        }
        __syncthreads();
    }

    const int col0 = bn + (lane & 15);
    const int row0 = bm + 16 * wave + (lane >> 4) * 4;
    #pragma unroll
    for (int nt = 0; nt < 4; nt++) {
        int col = col0 + 16 * nt;
        #pragma unroll
        for (int r = 0; r < 4; r++) {
            size_t off = (size_t)(row0 + r) * N + col;
            float v = acc[nt][r];
            if (EPI == 0) {
                Cb[off] = (bf16)v;
            } else if (EPI == 1) {
                Cb[off] = (bf16)fmaxf(v, 0.f);
            } else if (EPI == 2) {
                float xn = Xf[off] + v;
                Xf[off] = xn;
                Cb[off] = (bf16)xn;
            } else {
                Cf[off] = v;
            }
        }
    }
}

// ---------------------------------------------------------------- V transpose
// vt[((b*NH+n)*HD + h)*TT + t] = vb[(b*TT+t)*C + n*HD + h]
// One block per (t-tile 64, head, batch); LDS 64x64 tile transpose.
__global__ __launch_bounds__(256) void vtrans_kernel(
    const bf16* __restrict__ vb, bf16* __restrict__ vt)
{
    const int kt = blockIdx.x;
    const int n  = blockIdx.y;
    const int b  = blockIdx.z;
    const int tid = threadIdx.x;
    __shared__ __align__(16) bf16 tile[64][72];
    const int r = tid >> 2;
    const int c = (tid & 3) << 4;
    {
        const uint4* src = reinterpret_cast<const uint4*>(vb + (size_t)(b * TT + kt * 64 + r) * C + n * HD + c);
        uint4* dst = reinterpret_cast<uint4*>(&tile[r][c]);
        dst[0] = src[0];
        dst[1] = src[1];
    }
    __syncthreads();
    bf16 col[16];
    #pragma unroll
    for (int j = 0; j < 16; j++) col[j] = tile[c + j][r];
    uint4* dst = reinterpret_cast<uint4*>(vt + ((size_t)(b * NH + n) * HD + r) * TT + (size_t)kt * 64 + c);
    const uint4* srcp = reinterpret_cast<const uint4*>(col);
    dst[0] = srcp[0];
    dst[1] = srcp[1];
}

// ---------------------------------------------------------------- flash attention
// One block (4 waves) per (b, head, 64-row q-tile). Online softmax; MFMA for
// QK^T and PV. K staged [k][h]; V^T staged [h][k] (from pre-transposed vt);
// P routed through LDS to convert C/D layout -> A-operand layout.
// Fragment layouts (guide §3): A/B operand [idx16=lane&15][k=(lane>>4)*8+j];
// C/D: col = lane&15, row = (lane>>4)*4 + reg.
__global__ __launch_bounds__(256) void fattn_kernel(
    const bf16* __restrict__ qb, const bf16* __restrict__ kb,
    const bf16* __restrict__ vt, bf16* __restrict__ ob)
{
    const int qt  = blockIdx.x;   // q-tile 0..15
    const int n   = blockIdx.y;
    const int b   = blockIdx.z;
    const int tid  = threadIdx.x;
    const int lane = tid & 63;
    const int wave = tid >> 6;
    const int t0 = b * TT;

    __shared__ __align__(16) bf16 Ks[64][72];   // [k][h]
    __shared__ __align__(16) bf16 Vs[64][72];   // [h][k]  (V^T tile)
    __shared__ __align__(16) bf16 Ps[64][72];   // [q][k]

    const int m16  = lane & 15;
    const int koff = (lane >> 4) * 8;
    const int qrow_in = 16 * wave + (lane >> 4) * 4;   // tile-local q row of acc reg r=0

    // Q fragments (A operand) straight from global: rows qt*64+16w+m16, h contiguous
    bf16x8 qf[2];
    {
        const bf16* qrow = qb + (size_t)(t0 + qt * 64 + 16 * wave + m16) * C + n * HD;
        qf[0] = *reinterpret_cast<const bf16x8*>(qrow + koff);
        qf[1] = *reinterpret_cast<const bf16x8*>(qrow + 32 + koff);
    }

    f32x4 o_acc[4] = {};
    float mrow[4], lrow[4];
    #pragma unroll
    for (int r = 0; r < 4; r++) { mrow[r] = -1e30f; lrow[r] = 0.f; }

    const int r_st = tid >> 2;
    const int c_st = (tid & 3) << 4;

    for (int kt = 0; kt <= qt; kt++) {
        // stage K tile [k][h] (coalesced, 32B/thread)
        {
            const uint4* src = reinterpret_cast<const uint4*>(kb + (size_t)(t0 + kt * 64 + r_st) * C + n * HD + c_st);
            uint4* dst = reinterpret_cast<uint4*>(&Ks[r_st][c_st]);
            dst[0] = src[0];
            dst[1] = src[1];
        }
        // stage V^T tile [h][k] from pre-transposed vt (coalesced, 32B/thread)
        {
            const uint4* src = reinterpret_cast<const uint4*>(vt + ((size_t)(b * NH + n) * HD + r_st) * TT + (size_t)kt * 64 + c_st);
            uint4* dst = reinterpret_cast<uint4*>(&Vs[r_st][c_st]);
            dst[0] = src[0];
            dst[1] = src[1];
        }
        __syncthreads();

        // S = Q K^T : C/D frags, rows = q (16 per wave), cols = k (64)
        f32x4 s_acc[4] = {};
        #pragma unroll
        for (int ks = 0; ks < 2; ks++) {
            #pragma unroll
            for (int nt = 0; nt < 4; nt++) {
                bf16x8 kf = *reinterpret_cast<const bf16x8*>(&Ks[16 * nt + m16][32 * ks + koff]);
                s_acc[nt] = __builtin_amdgcn_mfma_f32_16x16x32_bf16(qf[ks], kf, s_acc[nt], 0, 0, 0);
            }
        }

        // scale + causal mask (only diagonal tile needs masking)
        #pragma unroll
        for (int nt = 0; nt < 4; nt++) {
            #pragma unroll
            for (int r = 0; r < 4; r++) s_acc[nt][r] *= 0.125f;   // 1/sqrt(64)
        }
        if (kt == qt) {
            #pragma unroll
            for (int nt = 0; nt < 4; nt++) {
                int col = m16 + 16 * nt;
                #pragma unroll
                for (int r = 0; r < 4; r++) {
                    if (col > qrow_in + r) s_acc[nt][r] = -1e30f;
                }
            }
        }

        // per-row max of this tile (reduce over nt, then over the 16-lane row group)
        float pmax[4];
        #pragma unroll
        for (int r = 0; r < 4; r++)
            pmax[r] = fmaxf(fmaxf(s_acc[0][r], s_acc[1][r]), fmaxf(s_acc[2][r], s_acc[3][r]));
        #pragma unroll
        for (int off = 8; off >= 1; off >>= 1) {
            #pragma unroll
            for (int r = 0; r < 4; r++) pmax[r] = fmaxf(pmax[r], __shfl_xor(pmax[r], off));
        }

        // online-softmax state update + rescale O
        #pragma unroll
        for (int r = 0; r < 4; r++) {
            float mnew = fmaxf(mrow[r], pmax[r]);
            float corr = __expf(mrow[r] - mnew);
            mrow[r] = mnew;
            lrow[r] *= corr;
            #pragma unroll
            for (int nt = 0; nt < 4; nt++) o_acc[nt][r] *= corr;
        }

        // P = exp(S - m): write bf16 to Ps (layout convert C/D -> [q][k]), sum rows
        float psum[4] = {0.f, 0.f, 0.f, 0.f};
        #pragma unroll
        for (int nt = 0; nt < 4; nt++) {
            int col = m16 + 16 * nt;
            #pragma unroll
            for (int r = 0; r < 4; r++) {
                float p = __expf(s_acc[nt][r] - mrow[r]);
                psum[r] += p;
                Ps[qrow_in + r][col] = (bf16)p;
            }
        }
        #pragma unroll
        for (int off = 8; off >= 1; off >>= 1) {
            #pragma unroll
            for (int r = 0; r < 4; r++) psum[r] += __shfl_xor(psum[r], off);
        }
        #pragma unroll
        for (int r = 0; r < 4; r++) lrow[r] += psum[r];

        __syncthreads();   // order Ps writes before A-frag reads (and wave convergence)

        // O += P V : A = Ps rows (this wave's q), B = Vs rows (h), contract over k
        #pragma unroll
        for (int ks = 0; ks < 2; ks++) {
            bf16x8 pf = *reinterpret_cast<const bf16x8*>(&Ps[16 * wave + m16][32 * ks + koff]);
            #pragma unroll
            for (int nt = 0; nt < 4; nt++) {
                bf16x8 vf = *reinterpret_cast<const bf16x8*>(&Vs[16 * nt + m16][32 * ks + koff]);
                o_acc[nt] = __builtin_amdgcn_mfma_f32_16x16x32_bf16(pf, vf, o_acc[nt], 0, 0, 0);
            }
        }
        __syncthreads();   // protect Ks/Vs before next stage
    }

    // epilogue: O /= l, store bf16
    #pragma unroll
    for (int r = 0; r < 4; r++) {
        float invl = 1.f / lrow[r];
        int q = qt * 64 + qrow_in + r;
        #pragma unroll
        for (int nt = 0; nt < 4; nt++) {
            ob[(size_t)(t0 + q) * C + n * HD + m16 + 16 * nt] = (bf16)(o_acc[nt][r] * invl);
        }
    }
}

// ---------------------------------------------------------------- launch
extern "C" void kernel_launch(void* const* d_in, const int* in_sizes, int n_in,
                              void* d_out, int out_size, void* d_ws, size_t ws_size,
                              hipStream_t stream) {
    const int*   idx    = (const int*)  d_in[0];
    const float* tok    = (const float*)d_in[1];
    const float* pos    = (const float*)d_in[2];
    const float* wk     = (const float*)d_in[3];
    const float* wq     = (const float*)d_in[4];
    const float* wv     = (const float*)d_in[5];
    const float* w_proj = (const float*)d_in[6];
    const float* w_in   = (const float*)d_in[7];
    const float* w_out  = (const float*)d_in[8];
    float* out = (float*)d_out;

    char* w = (char*)d_ws;
    float* xf = (float*)w;            w += (size_t)TOK * C * 4;   // 16 MB f32 master
    bf16* xb = (bf16*)w;              w += (size_t)TOK * C * 2;   // 8 MB
    bf16* kbuf = (bf16*)w;            w += (size_t)TOK * C * 2;
    bf16* vbuf = (bf16*)w;            w += (size_t)TOK * C * 2;
    bf16* qbuf = (bf16*)w;            w += (size_t)TOK * C * 2;
    bf16* obuf = (bf16*)w;            w += (size_t)TOK * C * 2;
    bf16* hbuf = (bf16*)w;            w += (size_t)TOK * FF * 2;  // 32 MB
    // vt aliases hbuf (8 MB of its 32 MB): vt lives between vtrans and fattn,
    // hbuf lives between FFN-in and FFN-out — stream-ordered, no overlap.
    bf16* vt = hbuf;

    embed_kernel<<<TOK * C / 256, 256, 0, stream>>>(idx, tok, pos, xf, xb);

    dim3 gC(C / 64, TOK / 64);     // N=1024 GEMMs
    dim3 gF(FF / 64, TOK / 64);    // N=4096 GEMM
    dim3 gV(VOC / 64, TOK / 64);   // logits

    for (int layer = 0; layer < 4; layer++) {
        // reference quirk: k<-wk, v<-wq, q<-wv
        gemm_kernel<0, 0><<<gC, 256, 0, stream>>>(xb, wk, kbuf, nullptr, nullptr, TOK, C, C);
        gemm_kernel<0, 0><<<gC, 256, 0, stream>>>(xb, wq, vbuf, nullptr, nullptr, TOK, C, C);
        gemm_kernel<0, 0><<<gC, 256, 0, stream>>>(xb, wv, qbuf, nullptr, nullptr, TOK, C, C);

        vtrans_kernel<<<dim3(TT / 64, NH, 4), 256, 0, stream>>>(vbuf, vt);
        fattn_kernel<<<dim3(TT / 64, NH, 4), 256, 0, stream>>>(qbuf, kbuf, vt, obuf);

        // x += o @ w_proj^T
        gemm_kernel<1, 2><<<gC, 256, 0, stream>>>(obuf, w_proj, xb, nullptr, xf, TOK, C, C);

        // h = relu(x @ w_in)
        gemm_kernel<0, 1><<<gF, 256, 0, stream>>>(xb, w_in, hbuf, nullptr, nullptr, TOK, FF, C);
        // x += h @ w_out
        gemm_kernel<0, 2><<<gC, 256, 0, stream>>>(hbuf, w_out, xb, nullptr, xf, TOK, C, FF);
    }

    // logits = x @ token_emb^T, f32 out
    gemm_kernel<1, 3><<<gV, 256, 0, stream>>>(xb, tok, nullptr, out, nullptr, TOK, VOC, C);
}

// Round 3
// 2139.522 us; speedup vs baseline: 5.7444x; 1.6307x over previous
//
#include <hip/hip_runtime.h>
#include <hip/hip_bf16.h>

// GPT fwd: B=4,T=1024,C=1024,H=16,Hd=64,L=4(shared weights),V=32000
// Inputs are FLOAT32 (per reference dtypes); output f32. Internals use bf16 MFMA
// with an f32 residual master. Quirk: k=x@wk(in3), v=x@wq(in4), q=x@wv(in5).
//
// R2: R1 design (pre-transposed bf16 weights, m97-style 128-tile GEMM with
// global_load_lds, fused QKV) with the workspace cut back to the proven 88 MiB:
// hbuf lives in d_out (dead until logits), tokT aliases weights+kvq+vt+obuf.
// XCD-aware block swizzle on all GEMMs (all grids divisible by 8).

using bf16 = __hip_bfloat16;
typedef __bf16 bf16x8 __attribute__((ext_vector_type(8)));
typedef float f32x4 __attribute__((ext_vector_type(4)));
typedef unsigned int u32;

#define TOK 4096      // B*T
#define C 1024
#define NH 16
#define HD 64
#define TT 1024
#define FF 4096
#define VOC 32000

__device__ __forceinline__ void gl_lds16(const bf16* g, bf16* s) {
    __builtin_amdgcn_global_load_lds(
        (const __attribute__((address_space(1))) u32*)g,
        (__attribute__((address_space(3))) u32*)s, 16, 0, 0);
}

// ---------------------------------------------------------------- embed
__global__ __launch_bounds__(256) void embed_kernel(
    const int* __restrict__ idx, const float* __restrict__ tok,
    const float* __restrict__ pos, float* __restrict__ xf, bf16* __restrict__ xb)
{
    int i = blockIdx.x * 256 + threadIdx.x;      // over TOK*C
    int t = i >> 10;            // token index 0..4095
    int c = i & 1023;
    int ti = t & 1023;          // position within sequence
    int v = idx[t];
    float val = tok[(size_t)v * C + c] + pos[(size_t)ti * C + c];
    xf[i] = val;
    xb[i] = (bf16)val;
}

// ---------------------------------------------------------------- weight prep
// Transpose f32 KxN -> bf16 NxK. Grid (N/64, K/64), 256 thr.
__global__ __launch_bounds__(256) void wtrans_kernel(
    const float* __restrict__ src, bf16* __restrict__ dst, int K, int N)
{
    __shared__ float tile[64][65];
    const int bk = blockIdx.y * 64;
    const int bn = blockIdx.x * 64;
    const int tid = threadIdx.x;
    const int r = tid >> 4;            // 0..15
    const int c = (tid & 15) * 4;
    #pragma unroll
    for (int p = 0; p < 4; p++) {
        float4 f = *reinterpret_cast<const float4*>(src + (size_t)(bk + p * 16 + r) * N + bn + c);
        tile[p * 16 + r][c + 0] = f.x;
        tile[p * 16 + r][c + 1] = f.y;
        tile[p * 16 + r][c + 2] = f.z;
        tile[p * 16 + r][c + 3] = f.w;
    }
    __syncthreads();
    const int n = tid >> 2;            // 0..63
    const int k0 = (tid & 3) * 16;
    bf16 vals[16];
    #pragma unroll
    for (int j = 0; j < 16; j++) vals[j] = (bf16)tile[k0 + j][n];
    uint4* d = reinterpret_cast<uint4*>(dst + (size_t)(bn + n) * K + bk + k0);
    d[0] = reinterpret_cast<const uint4*>(vals)[0];
    d[1] = reinterpret_cast<const uint4*>(vals)[1];
}

// Convert f32 -> bf16 elementwise (layout preserved). 8 elems/thread.
__global__ __launch_bounds__(256) void wconv_kernel(
    const float* __restrict__ src, bf16* __restrict__ dst)
{
    size_t i = ((size_t)blockIdx.x * 256 + threadIdx.x) * 8;
    float4 a = *reinterpret_cast<const float4*>(src + i);
    float4 b = *reinterpret_cast<const float4*>(src + i + 4);
    bf16 v[8] = {(bf16)a.x, (bf16)a.y, (bf16)a.z, (bf16)a.w,
                 (bf16)b.x, (bf16)b.y, (bf16)b.z, (bf16)b.w};
    *reinterpret_cast<uint4*>(dst + i) = *reinterpret_cast<const uint4*>(v);
}

// ---------------------------------------------------------------- GEMM (m97 structure)
// C[M,N] (+)= A[M,K] @ Bt^T, A bf16 MxK, Bt bf16 NxK (row-major, contiguous K).
// BM=128, BN=NT*32 (NT=4 -> 128, NT=2 -> 64). BK=64. 4 waves as 2x2.
// Staging: global_load_lds width-16, linear LDS [row][k] (no padding -- required).
// XCD-aware block swizzle (grid count divisible by 8 for all our launches).
// EPI: 0 = store bf16; 1 = relu+bf16; 2 = Xf += acc, Cb=bf16(Xf); 3 = store f32.
template <int EPI, int NT>
__global__ __launch_bounds__(256) void gemm128_kernel(
    const bf16* __restrict__ A, const bf16* __restrict__ Bt,
    bf16* __restrict__ Cb, float* __restrict__ Cf, float* __restrict__ Xf,
    int M, int N, int K)
{
    constexpr int BN = NT * 32;
    __shared__ __align__(16) bf16 As[128 * 64];
    __shared__ __align__(16) bf16 Bs[BN * 64];
    const int tid = threadIdx.x;
    const int lane = tid & 63;
    const int wave = tid >> 6;
    const int wr = wave >> 1;          // m-half 0..1
    const int wc = wave & 1;           // n-half 0..1

    // XCD swizzle: contiguous chunks per XCD (nwg % 8 == 0 for all launches)
    const int gx = gridDim.x;
    const int nwg = gx * gridDim.y;
    int wgid = blockIdx.y * gx + blockIdx.x;
    const int cpx = nwg >> 3;
    wgid = (wgid & 7) * cpx + (wgid >> 3);
    const int bm = (wgid / gx) * 128;
    const int bn = (wgid % gx) * BN;

    f32x4 acc[4][NT] = {};

    const int srow = tid >> 3;         // 0..31 (pass adds 32)
    const int scol = (tid & 7) * 8;    // bf16 col chunk

    const int m16 = lane & 15;
    const int koff = (lane >> 4) * 8;

    for (int kc = 0; kc < K; kc += 64) {
        #pragma unroll
        for (int p = 0; p < 4; p++) {
            int row = p * 32 + srow;
            gl_lds16(A + (size_t)(bm + row) * K + kc + scol, As + row * 64 + scol);
        }
        #pragma unroll
        for (int p = 0; p < BN / 32; p++) {
            int row = p * 32 + srow;
            gl_lds16(Bt + (size_t)(bn + row) * K + kc + scol, Bs + row * 64 + scol);
        }
        __syncthreads();

        #pragma unroll
        for (int ks = 0; ks < 2; ks++) {
            bf16x8 bfr[NT];
            #pragma unroll
            for (int j = 0; j < NT; j++)
                bfr[j] = *reinterpret_cast<const bf16x8*>(Bs + (wc * (NT * 16) + j * 16 + m16) * 64 + ks * 32 + koff);
            #pragma unroll
            for (int i = 0; i < 4; i++) {
                bf16x8 afr = *reinterpret_cast<const bf16x8*>(As + (wr * 64 + i * 16 + m16) * 64 + ks * 32 + koff);
                #pragma unroll
                for (int j = 0; j < NT; j++)
                    acc[i][j] = __builtin_amdgcn_mfma_f32_16x16x32_bf16(afr, bfr[j], acc[i][j], 0, 0, 0);
            }
        }
        __syncthreads();
    }

    // epilogue: C/D layout col = lane&15, row = (lane>>4)*4 + r
    const int r0 = (lane >> 4) * 4;
    #pragma unroll
    for (int i = 0; i < 4; i++) {
        int row = bm + wr * 64 + i * 16 + r0;
        #pragma unroll
        for (int j = 0; j < NT; j++) {
            int col = bn + wc * (NT * 16) + j * 16 + m16;
            #pragma unroll
            for (int r = 0; r < 4; r++) {
                size_t off = (size_t)(row + r) * N + col;
                float v = acc[i][j][r];
                if (EPI == 0) {
                    Cb[off] = (bf16)v;
                } else if (EPI == 1) {
                    Cb[off] = (bf16)fmaxf(v, 0.f);
                } else if (EPI == 2) {
                    float xn = Xf[off] + v;
                    Xf[off] = xn;
                    Cb[off] = (bf16)xn;
                } else {
                    Cf[off] = v;
                }
            }
        }
    }
}

// ---------------------------------------------------------------- V transpose
// vt[((b*NH+n)*HD + h)*TT + t] = vb[(b*TT+t)*ld + n*HD + h]
__global__ __launch_bounds__(256) void vtrans_kernel(
    const bf16* __restrict__ vb, bf16* __restrict__ vt, int ld)
{
    const int kt = blockIdx.x;
    const int n  = blockIdx.y;
    const int b  = blockIdx.z;
    const int tid = threadIdx.x;
    __shared__ __align__(16) bf16 tile[64][72];
    const int r = tid >> 2;
    const int c = (tid & 3) << 4;
    {
        const uint4* src = reinterpret_cast<const uint4*>(vb + (size_t)(b * TT + kt * 64 + r) * ld + n * HD + c);
        uint4* dst = reinterpret_cast<uint4*>(&tile[r][c]);
        dst[0] = src[0];
        dst[1] = src[1];
    }
    __syncthreads();
    bf16 col[16];
    #pragma unroll
    for (int j = 0; j < 16; j++) col[j] = tile[c + j][r];
    uint4* dst = reinterpret_cast<uint4*>(vt + ((size_t)(b * NH + n) * HD + r) * TT + (size_t)kt * 64 + c);
    const uint4* srcp = reinterpret_cast<const uint4*>(col);
    dst[0] = srcp[0];
    dst[1] = srcp[1];
}

// ---------------------------------------------------------------- flash attention
// One block (4 waves) per (b, head, 64-row q-tile). Online softmax; MFMA for
// QK^T and PV. q/k read with row stride ld (fused QKV buffer); V^T pre-transposed.
__global__ __launch_bounds__(256) void fattn_kernel(
    const bf16* __restrict__ qb, const bf16* __restrict__ kb,
    const bf16* __restrict__ vt, bf16* __restrict__ ob, int ld)
{
    const int qt  = blockIdx.x;   // q-tile 0..15
    const int n   = blockIdx.y;
    const int b   = blockIdx.z;
    const int tid  = threadIdx.x;
    const int lane = tid & 63;
    const int wave = tid >> 6;
    const int t0 = b * TT;

    __shared__ __align__(16) bf16 Ks[64][72];   // [k][h]
    __shared__ __align__(16) bf16 Vs[64][72];   // [h][k]  (V^T tile)
    __shared__ __align__(16) bf16 Ps[64][72];   // [q][k]

    const int m16  = lane & 15;
    const int koff = (lane >> 4) * 8;
    const int qrow_in = 16 * wave + (lane >> 4) * 4;

    bf16x8 qf[2];
    {
        const bf16* qrow = qb + (size_t)(t0 + qt * 64 + 16 * wave + m16) * ld + n * HD;
        qf[0] = *reinterpret_cast<const bf16x8*>(qrow + koff);
        qf[1] = *reinterpret_cast<const bf16x8*>(qrow + 32 + koff);
    }

    f32x4 o_acc[4] = {};
    float mrow[4], lrow[4];
    #pragma unroll
    for (int r = 0; r < 4; r++) { mrow[r] = -1e30f; lrow[r] = 0.f; }

    const int r_st = tid >> 2;
    const int c_st = (tid & 3) << 4;

    for (int kt = 0; kt <= qt; kt++) {
        {
            const uint4* src = reinterpret_cast<const uint4*>(kb + (size_t)(t0 + kt * 64 + r_st) * ld + n * HD + c_st);
            uint4* dst = reinterpret_cast<uint4*>(&Ks[r_st][c_st]);
            dst[0] = src[0];
            dst[1] = src[1];
        }
        {
            const uint4* src = reinterpret_cast<const uint4*>(vt + ((size_t)(b * NH + n) * HD + r_st) * TT + (size_t)kt * 64 + c_st);
            uint4* dst = reinterpret_cast<uint4*>(&Vs[r_st][c_st]);
            dst[0] = src[0];
            dst[1] = src[1];
        }
        __syncthreads();

        // S = Q K^T
        f32x4 s_acc[4] = {};
        #pragma unroll
        for (int ks = 0; ks < 2; ks++) {
            #pragma unroll
            for (int nt = 0; nt < 4; nt++) {
                bf16x8 kf = *reinterpret_cast<const bf16x8*>(&Ks[16 * nt + m16][32 * ks + koff]);
                s_acc[nt] = __builtin_amdgcn_mfma_f32_16x16x32_bf16(qf[ks], kf, s_acc[nt], 0, 0, 0);
            }
        }

        #pragma unroll
        for (int nt = 0; nt < 4; nt++) {
            #pragma unroll
            for (int r = 0; r < 4; r++) s_acc[nt][r] *= 0.125f;   // 1/sqrt(64)
        }
        if (kt == qt) {
            #pragma unroll
            for (int nt = 0; nt < 4; nt++) {
                int col = m16 + 16 * nt;
                #pragma unroll
                for (int r = 0; r < 4; r++) {
                    if (col > qrow_in + r) s_acc[nt][r] = -1e30f;
                }
            }
        }

        float pmax[4];
        #pragma unroll
        for (int r = 0; r < 4; r++)
            pmax[r] = fmaxf(fmaxf(s_acc[0][r], s_acc[1][r]), fmaxf(s_acc[2][r], s_acc[3][r]));
        #pragma unroll
        for (int off = 8; off >= 1; off >>= 1) {
            #pragma unroll
            for (int r = 0; r < 4; r++) pmax[r] = fmaxf(pmax[r], __shfl_xor(pmax[r], off));
        }

        #pragma unroll
        for (int r = 0; r < 4; r++) {
            float mnew = fmaxf(mrow[r], pmax[r]);
            float corr = __expf(mrow[r] - mnew);
            mrow[r] = mnew;
            lrow[r] *= corr;
            #pragma unroll
            for (int nt = 0; nt < 4; nt++) o_acc[nt][r] *= corr;
        }

        float psum[4] = {0.f, 0.f, 0.f, 0.f};
        #pragma unroll
        for (int nt = 0; nt < 4; nt++) {
            int col = m16 + 16 * nt;
            #pragma unroll
            for (int r = 0; r < 4; r++) {
                float p = __expf(s_acc[nt][r] - mrow[r]);
                psum[r] += p;
                Ps[qrow_in + r][col] = (bf16)p;
            }
        }
        #pragma unroll
        for (int off = 8; off >= 1; off >>= 1) {
            #pragma unroll
            for (int r = 0; r < 4; r++) psum[r] += __shfl_xor(psum[r], off);
        }
        #pragma unroll
        for (int r = 0; r < 4; r++) lrow[r] += psum[r];

        __syncthreads();   // Ps writes before reads

        #pragma unroll
        for (int ks = 0; ks < 2; ks++) {
            bf16x8 pf = *reinterpret_cast<const bf16x8*>(&Ps[16 * wave + m16][32 * ks + koff]);
            #pragma unroll
            for (int nt = 0; nt < 4; nt++) {
                bf16x8 vf = *reinterpret_cast<const bf16x8*>(&Vs[16 * nt + m16][32 * ks + koff]);
                o_acc[nt] = __builtin_amdgcn_mfma_f32_16x16x32_bf16(pf, vf, o_acc[nt], 0, 0, 0);
            }
        }
        __syncthreads();   // protect Ks/Vs
    }

    #pragma unroll
    for (int r = 0; r < 4; r++) {
        float invl = 1.f / lrow[r];
        int q = qt * 64 + qrow_in + r;
        #pragma unroll
        for (int nt = 0; nt < 4; nt++) {
            ob[(size_t)(t0 + q) * C + n * HD + m16 + 16 * nt] = (bf16)(o_acc[nt][r] * invl);
        }
    }
}

// ---------------------------------------------------------------- launch
extern "C" void kernel_launch(void* const* d_in, const int* in_sizes, int n_in,
                              void* d_out, int out_size, void* d_ws, size_t ws_size,
                              hipStream_t stream) {
    const int*   idx    = (const int*)  d_in[0];
    const float* tok    = (const float*)d_in[1];
    const float* pos    = (const float*)d_in[2];
    const float* wk     = (const float*)d_in[3];
    const float* wq     = (const float*)d_in[4];
    const float* wv     = (const float*)d_in[5];
    const float* w_proj = (const float*)d_in[6];
    const float* w_in   = (const float*)d_in[7];
    const float* w_out  = (const float*)d_in[8];
    float* out = (float*)d_out;

    // Workspace layout: exactly 88 MiB (the proven-safe footprint).
    //   xf 16 | xb 8 | [wqkvT 6 | wpT 2 | w_inT 8 | w_outT 8 | kvq 24 | vt 8 | obuf 8]
    // tokT (62.5 MiB, live only for logits) aliases the bracketed 64 MiB region
    // (weights + activations all dead by then).
    // hbuf (32 MiB, live FFN-in -> FFN-out) lives in d_out (500 MiB, dead until
    // the logits GEMM overwrites it). Stream-ordered, no overlap.
    char* w = (char*)d_ws;
    float* xf     = (float*)w;   w += (size_t)TOK * C * 4;    // 16 MiB f32 master
    bf16* xb      = (bf16*)w;    w += (size_t)TOK * C * 2;    //  8 MiB
    char* alias0  = w;
    bf16* wqkvT   = (bf16*)w;    w += (size_t)3 * C * C * 2;  //  6 MiB (rows: k|v|q per quirk)
    bf16* wpT     = (bf16*)w;    w += (size_t)C * C * 2;      //  2 MiB
    bf16* w_inT   = (bf16*)w;    w += (size_t)C * FF * 2;     //  8 MiB
    bf16* w_outT  = (bf16*)w;    w += (size_t)C * FF * 2;     //  8 MiB
    bf16* kvq     = (bf16*)w;    w += (size_t)TOK * 3 * C * 2;// 24 MiB
    bf16* vt      = (bf16*)w;    w += (size_t)TOK * C * 2;    //  8 MiB
    bf16* obuf    = (bf16*)w;    w += (size_t)TOK * C * 2;    //  8 MiB
    bf16* tokT = (bf16*)alias0;          // needs 62.5 MiB <= 64 MiB region
    bf16* hbuf = (bf16*)d_out;           // 32 MiB of the 500 MiB output buffer

    embed_kernel<<<TOK * C / 256, 256, 0, stream>>>(idx, tok, pos, xf, xb);

    // weight prep (once): transpose KxN f32 -> NxK bf16; convert NxK f32 -> bf16
    wtrans_kernel<<<dim3(C / 64, C / 64), 256, 0, stream>>>(wk, wqkvT, C, C);
    wtrans_kernel<<<dim3(C / 64, C / 64), 256, 0, stream>>>(wq, wqkvT + (size_t)C * C, C, C);
    wtrans_kernel<<<dim3(C / 64, C / 64), 256, 0, stream>>>(wv, wqkvT + (size_t)2 * C * C, C, C);
    wtrans_kernel<<<dim3(FF / 64, C / 64), 256, 0, stream>>>(w_in, w_inT, C, FF);
    wtrans_kernel<<<dim3(C / 64, FF / 64), 256, 0, stream>>>(w_out, w_outT, FF, C);
    wconv_kernel<<<C * C / 2048, 256, 0, stream>>>(w_proj, wpT);   // already NxK

    dim3 gQKV(3 * C / 128, TOK / 128);   // (24, 32)  768 wgs
    dim3 gCn(C / 64, TOK / 128);         // (16, 32)  512 wgs (NT=2 -> BN=64)
    dim3 gF(FF / 128, TOK / 128);        // (32, 32)  1024 wgs
    dim3 gV(VOC / 128, TOK / 128);       // (250, 32) 8000 wgs

    for (int layer = 0; layer < 4; layer++) {
        // fused QKV: cols 0..C-1 = x@wk (k), C..2C-1 = x@wq (v), 2C..3C-1 = x@wv (q)
        gemm128_kernel<0, 4><<<gQKV, 256, 0, stream>>>(xb, wqkvT, kvq, nullptr, nullptr, TOK, 3 * C, C);

        vtrans_kernel<<<dim3(TT / 64, NH, 4), 256, 0, stream>>>(kvq + C, vt, 3 * C);
        fattn_kernel<<<dim3(TT / 64, NH, 4), 256, 0, stream>>>(kvq + 2 * C, kvq, vt, obuf, 3 * C);

        // x += o @ w_proj^T
        gemm128_kernel<2, 2><<<gCn, 256, 0, stream>>>(obuf, wpT, xb, nullptr, xf, TOK, C, C);
        // h = relu(x @ w_in)
        gemm128_kernel<1, 4><<<gF, 256, 0, stream>>>(xb, w_inT, hbuf, nullptr, nullptr, TOK, FF, C);
        // x += h @ w_out
        gemm128_kernel<2, 2><<<gCn, 256, 0, stream>>>(hbuf, w_outT, xb, nullptr, xf, TOK, C, FF);
    }

    // logits = x @ token_emb^T (tokT bf16 NxK), f32 out
    wconv_kernel<<<VOC * C / 2048, 256, 0, stream>>>(tok, tokT);
    gemm128_kernel<3, 4><<<gV, 256, 0, stream>>>(xb, tokT, nullptr, out, nullptr, TOK, VOC, C);
}

// Round 5
// 2111.312 us; speedup vs baseline: 5.8211x; 1.0134x over previous
//
#include <hip/hip_runtime.h>
#include <hip/hip_bf16.h>

// GPT fwd: B=4,T=1024,C=1024,H=16,Hd=64,L=4(shared weights),V=32000
// Inputs are FLOAT32 (per reference dtypes); output f32. Internals use bf16 MFMA
// with an f32 residual master. Quirk: k=x@wk(in3), v=x@wq(in4), q=x@wv(in5).
//
// R5 == R4 resubmission (audited, no fault found; prior failure attributed to
// infra degradation visible in R3's 53-min npz pushes):
// (1) nontemporal stores for the 512 MB f32 logits output (stops L3 thrash,
// keeps tokT resident -> less HBM refetch); (2) fattn q-tile 64 -> 128 rows
// (halves staging/barrier cost per q-row) with robust masked-tile clamp;
// (3) defer-max (T13, THR=8) in fattn.

using bf16 = __hip_bfloat16;
typedef __bf16 bf16x8 __attribute__((ext_vector_type(8)));
typedef float f32x4 __attribute__((ext_vector_type(4)));
typedef unsigned int u32;

#define TOK 4096      // B*T
#define C 1024
#define NH 16
#define HD 64
#define TT 1024
#define FF 4096
#define VOC 32000

__device__ __forceinline__ void gl_lds16(const bf16* g, bf16* s) {
    __builtin_amdgcn_global_load_lds(
        (const __attribute__((address_space(1))) u32*)g,
        (__attribute__((address_space(3))) u32*)s, 16, 0, 0);
}

// ---------------------------------------------------------------- embed
__global__ __launch_bounds__(256) void embed_kernel(
    const int* __restrict__ idx, const float* __restrict__ tok,
    const float* __restrict__ pos, float* __restrict__ xf, bf16* __restrict__ xb)
{
    int i = blockIdx.x * 256 + threadIdx.x;      // over TOK*C
    int t = i >> 10;            // token index 0..4095
    int c = i & 1023;
    int ti = t & 1023;          // position within sequence
    int v = idx[t];
    float val = tok[(size_t)v * C + c] + pos[(size_t)ti * C + c];
    xf[i] = val;
    xb[i] = (bf16)val;
}

// ---------------------------------------------------------------- weight prep
// Transpose f32 KxN -> bf16 NxK. Grid (N/64, K/64), 256 thr.
__global__ __launch_bounds__(256) void wtrans_kernel(
    const float* __restrict__ src, bf16* __restrict__ dst, int K, int N)
{
    __shared__ float tile[64][65];
    const int bk = blockIdx.y * 64;
    const int bn = blockIdx.x * 64;
    const int tid = threadIdx.x;
    const int r = tid >> 4;            // 0..15
    const int c = (tid & 15) * 4;
    #pragma unroll
    for (int p = 0; p < 4; p++) {
        float4 f = *reinterpret_cast<const float4*>(src + (size_t)(bk + p * 16 + r) * N + bn + c);
        tile[p * 16 + r][c + 0] = f.x;
        tile[p * 16 + r][c + 1] = f.y;
        tile[p * 16 + r][c + 2] = f.z;
        tile[p * 16 + r][c + 3] = f.w;
    }
    __syncthreads();
    const int n = tid >> 2;            // 0..63
    const int k0 = (tid & 3) * 16;
    bf16 vals[16];
    #pragma unroll
    for (int j = 0; j < 16; j++) vals[j] = (bf16)tile[k0 + j][n];
    uint4* d = reinterpret_cast<uint4*>(dst + (size_t)(bn + n) * K + bk + k0);
    d[0] = reinterpret_cast<const uint4*>(vals)[0];
    d[1] = reinterpret_cast<const uint4*>(vals)[1];
}

// Convert f32 -> bf16 elementwise (layout preserved). 8 elems/thread.
__global__ __launch_bounds__(256) void wconv_kernel(
    const float* __restrict__ src, bf16* __restrict__ dst)
{
    size_t i = ((size_t)blockIdx.x * 256 + threadIdx.x) * 8;
    float4 a = *reinterpret_cast<const float4*>(src + i);
    float4 b = *reinterpret_cast<const float4*>(src + i + 4);
    bf16 v[8] = {(bf16)a.x, (bf16)a.y, (bf16)a.z, (bf16)a.w,
                 (bf16)b.x, (bf16)b.y, (bf16)b.z, (bf16)b.w};
    *reinterpret_cast<uint4*>(dst + i) = *reinterpret_cast<const uint4*>(v);
}

// ---------------------------------------------------------------- GEMM (m97 structure)
// C[M,N] (+)= A[M,K] @ Bt^T, A bf16 MxK, Bt bf16 NxK (row-major, contiguous K).
// BM=128, BN=NT*32 (NT=4 -> 128, NT=2 -> 64). BK=64. 4 waves as 2x2.
// Staging: global_load_lds width-16, linear LDS [row][k] (no padding -- required).
// XCD-aware block swizzle (grid count divisible by 8 for all our launches).
// EPI: 0 = store bf16; 1 = relu+bf16; 2 = Xf += acc, Cb=bf16(Xf);
//      3 = store f32 NONTEMPORAL (write-once logits; keeps B operand L3-resident).
template <int EPI, int NT>
__global__ __launch_bounds__(256) void gemm128_kernel(
    const bf16* __restrict__ A, const bf16* __restrict__ Bt,
    bf16* __restrict__ Cb, float* __restrict__ Cf, float* __restrict__ Xf,
    int M, int N, int K)
{
    constexpr int BN = NT * 32;
    __shared__ __align__(16) bf16 As[128 * 64];
    __shared__ __align__(16) bf16 Bs[BN * 64];
    const int tid = threadIdx.x;
    const int lane = tid & 63;
    const int wave = tid >> 6;
    const int wr = wave >> 1;          // m-half 0..1
    const int wc = wave & 1;           // n-half 0..1

    // XCD swizzle: contiguous chunks per XCD (nwg % 8 == 0 for all launches)
    const int gx = gridDim.x;
    const int nwg = gx * gridDim.y;
    int wgid = blockIdx.y * gx + blockIdx.x;
    const int cpx = nwg >> 3;
    wgid = (wgid & 7) * cpx + (wgid >> 3);
    const int bm = (wgid / gx) * 128;
    const int bn = (wgid % gx) * BN;

    f32x4 acc[4][NT] = {};

    const int srow = tid >> 3;         // 0..31 (pass adds 32)
    const int scol = (tid & 7) * 8;    // bf16 col chunk

    const int m16 = lane & 15;
    const int koff = (lane >> 4) * 8;

    for (int kc = 0; kc < K; kc += 64) {
        #pragma unroll
        for (int p = 0; p < 4; p++) {
            int row = p * 32 + srow;
            gl_lds16(A + (size_t)(bm + row) * K + kc + scol, As + row * 64 + scol);
        }
        #pragma unroll
        for (int p = 0; p < BN / 32; p++) {
            int row = p * 32 + srow;
            gl_lds16(Bt + (size_t)(bn + row) * K + kc + scol, Bs + row * 64 + scol);
        }
        __syncthreads();

        #pragma unroll
        for (int ks = 0; ks < 2; ks++) {
            bf16x8 bfr[NT];
            #pragma unroll
            for (int j = 0; j < NT; j++)
                bfr[j] = *reinterpret_cast<const bf16x8*>(Bs + (wc * (NT * 16) + j * 16 + m16) * 64 + ks * 32 + koff);
            #pragma unroll
            for (int i = 0; i < 4; i++) {
                bf16x8 afr = *reinterpret_cast<const bf16x8*>(As + (wr * 64 + i * 16 + m16) * 64 + ks * 32 + koff);
                #pragma unroll
                for (int j = 0; j < NT; j++)
                    acc[i][j] = __builtin_amdgcn_mfma_f32_16x16x32_bf16(afr, bfr[j], acc[i][j], 0, 0, 0);
            }
        }
        __syncthreads();
    }

    // epilogue: C/D layout col = lane&15, row = (lane>>4)*4 + r
    const int r0 = (lane >> 4) * 4;
    #pragma unroll
    for (int i = 0; i < 4; i++) {
        int row = bm + wr * 64 + i * 16 + r0;
        #pragma unroll
        for (int j = 0; j < NT; j++) {
            int col = bn + wc * (NT * 16) + j * 16 + m16;
            #pragma unroll
            for (int r = 0; r < 4; r++) {
                size_t off = (size_t)(row + r) * N + col;
                float v = acc[i][j][r];
                if (EPI == 0) {
                    Cb[off] = (bf16)v;
                } else if (EPI == 1) {
                    Cb[off] = (bf16)fmaxf(v, 0.f);
                } else if (EPI == 2) {
                    float xn = Xf[off] + v;
                    Xf[off] = xn;
                    Cb[off] = (bf16)xn;
                } else {
                    __builtin_nontemporal_store(v, &Cf[off]);
                }
            }
        }
    }
}

// ---------------------------------------------------------------- V transpose
// vt[((b*NH+n)*HD + h)*TT + t] = vb[(b*TT+t)*ld + n*HD + h]
__global__ __launch_bounds__(256) void vtrans_kernel(
    const bf16* __restrict__ vb, bf16* __restrict__ vt, int ld)
{
    const int kt = blockIdx.x;
    const int n  = blockIdx.y;
    const int b  = blockIdx.z;
    const int tid = threadIdx.x;
    __shared__ __align__(16) bf16 tile[64][72];
    const int r = tid >> 2;
    const int c = (tid & 3) << 4;
    {
        const uint4* src = reinterpret_cast<const uint4*>(vb + (size_t)(b * TT + kt * 64 + r) * ld + n * HD + c);
        uint4* dst = reinterpret_cast<uint4*>(&tile[r][c]);
        dst[0] = src[0];
        dst[1] = src[1];
    }
    __syncthreads();
    bf16 col[16];
    #pragma unroll
    for (int j = 0; j < 16; j++) col[j] = tile[c + j][r];
    uint4* dst = reinterpret_cast<uint4*>(vt + ((size_t)(b * NH + n) * HD + r) * TT + (size_t)kt * 64 + c);
    const uint4* srcp = reinterpret_cast<const uint4*>(col);
    dst[0] = srcp[0];
    dst[1] = srcp[1];
}

// ---------------------------------------------------------------- flash attention
// One block (4 waves) per (b, head, 128-row q-tile); each wave owns 32 q-rows.
// KV tile = 64 keys. Online softmax with defer-max (THR=8); MFMA for QK^T and PV.
// Masked entries are clamped via (s <= -1e29 -> p = 0): with QBLK=128, waves 0/1
// see FULLY-masked diagonal tiles where exp(-1e30 - (-1e30)) would give p=1.
__global__ __launch_bounds__(256) void fattn_kernel(
    const bf16* __restrict__ qb, const bf16* __restrict__ kb,
    const bf16* __restrict__ vt, bf16* __restrict__ ob, int ld)
{
    const int qt  = blockIdx.x;   // q-tile 0..7 (128 rows each)
    const int n   = blockIdx.y;
    const int b   = blockIdx.z;
    const int tid  = threadIdx.x;
    const int lane = tid & 63;
    const int wave = tid >> 6;
    const int t0 = b * TT;

    __shared__ __align__(16) bf16 Ks[64][72];    // [k][h]
    __shared__ __align__(16) bf16 Vs[64][72];    // [h][k]  (V^T tile)
    __shared__ __align__(16) bf16 Ps[128][72];   // [q][k]

    const int m16  = lane & 15;
    const int koff = (lane >> 4) * 8;
    const int r4   = (lane >> 4) * 4;            // C/D row base within 16-tile
    const int qbase = wave * 32;                 // wave's q-row base within 128-tile

    // Q fragments: 2 row-tiles x 2 k-slices
    bf16x8 qf[2][2];
    #pragma unroll
    for (int i = 0; i < 2; i++) {
        const bf16* qrow = qb + (size_t)(t0 + qt * 128 + qbase + i * 16 + m16) * ld + n * HD;
        qf[i][0] = *reinterpret_cast<const bf16x8*>(qrow + koff);
        qf[i][1] = *reinterpret_cast<const bf16x8*>(qrow + 32 + koff);
    }

    f32x4 o_acc[2][4] = {};
    float mrow[2][4], lrow[2][4];
    #pragma unroll
    for (int i = 0; i < 2; i++)
        #pragma unroll
        for (int r = 0; r < 4; r++) { mrow[i][r] = -1e30f; lrow[i][r] = 0.f; }

    const int r_st = tid >> 2;          // 0..63
    const int c_st = (tid & 3) << 4;    // 0,16,32,48

    const int ktmax = 2 * qt + 1;
    for (int kt = 0; kt <= ktmax; kt++) {
        {
            const uint4* src = reinterpret_cast<const uint4*>(kb + (size_t)(t0 + kt * 64 + r_st) * ld + n * HD + c_st);
            uint4* dst = reinterpret_cast<uint4*>(&Ks[r_st][c_st]);
            dst[0] = src[0];
            dst[1] = src[1];
        }
        {
            const uint4* src = reinterpret_cast<const uint4*>(vt + ((size_t)(b * NH + n) * HD + r_st) * TT + (size_t)kt * 64 + c_st);
            uint4* dst = reinterpret_cast<uint4*>(&Vs[r_st][c_st]);
            dst[0] = src[0];
            dst[1] = src[1];
        }
        __syncthreads();

        // S = Q K^T  (2 row-tiles x 4 col-tiles)
        f32x4 s_acc[2][4] = {};
        #pragma unroll
        for (int ks = 0; ks < 2; ks++) {
            bf16x8 kfr[4];
            #pragma unroll
            for (int nt = 0; nt < 4; nt++)
                kfr[nt] = *reinterpret_cast<const bf16x8*>(&Ks[16 * nt + m16][32 * ks + koff]);
            #pragma unroll
            for (int i = 0; i < 2; i++)
                #pragma unroll
                for (int nt = 0; nt < 4; nt++)
                    s_acc[i][nt] = __builtin_amdgcn_mfma_f32_16x16x32_bf16(qf[i][ks], kfr[nt], s_acc[i][nt], 0, 0, 0);
        }

        // scale + causal mask (tiles overlapping the diagonal)
        #pragma unroll
        for (int i = 0; i < 2; i++)
            #pragma unroll
            for (int nt = 0; nt < 4; nt++)
                #pragma unroll
                for (int r = 0; r < 4; r++) s_acc[i][nt][r] *= 0.125f;   // 1/sqrt(64)
        if (kt >= 2 * qt) {   // only the last two tiles can touch the diagonal
            #pragma unroll
            for (int i = 0; i < 2; i++) {
                int rowg = qt * 128 + qbase + i * 16 + r4;
                #pragma unroll
                for (int nt = 0; nt < 4; nt++) {
                    int colg = kt * 64 + m16 + 16 * nt;
                    #pragma unroll
                    for (int r = 0; r < 4; r++)
                        if (colg > rowg + r) s_acc[i][nt][r] = -1e30f;
                }
            }
        }

        // per-row tile max
        float pmax[2][4];
        #pragma unroll
        for (int i = 0; i < 2; i++)
            #pragma unroll
            for (int r = 0; r < 4; r++)
                pmax[i][r] = fmaxf(fmaxf(s_acc[i][0][r], s_acc[i][1][r]),
                                   fmaxf(s_acc[i][2][r], s_acc[i][3][r]));
        #pragma unroll
        for (int off = 8; off >= 1; off >>= 1)
            #pragma unroll
            for (int i = 0; i < 2; i++)
                #pragma unroll
                for (int r = 0; r < 4; r++)
                    pmax[i][r] = fmaxf(pmax[i][r], __shfl_xor(pmax[i][r], off));

        // defer-max (T13): only rescale when the max grew by > 8
        float dm = -1e30f;
        #pragma unroll
        for (int i = 0; i < 2; i++)
            #pragma unroll
            for (int r = 0; r < 4; r++)
                dm = fmaxf(dm, pmax[i][r] - mrow[i][r]);
        if (__any(dm > 8.f)) {
            #pragma unroll
            for (int i = 0; i < 2; i++)
                #pragma unroll
                for (int r = 0; r < 4; r++) {
                    float mnew = fmaxf(mrow[i][r], pmax[i][r]);
                    float corr = __expf(mrow[i][r] - mnew);
                    mrow[i][r] = mnew;
                    lrow[i][r] *= corr;
                    #pragma unroll
                    for (int nt = 0; nt < 4; nt++) o_acc[i][nt][r] *= corr;
                }
        }

        // P = exp(S - m) with masked-entry clamp; write bf16 Ps; accumulate row sums
        float psum[2][4] = {};
        #pragma unroll
        for (int i = 0; i < 2; i++) {
            #pragma unroll
            for (int nt = 0; nt < 4; nt++) {
                int col = m16 + 16 * nt;
                #pragma unroll
                for (int r = 0; r < 4; r++) {
                    float sv = s_acc[i][nt][r];
                    float p = __expf(sv - mrow[i][r]);
                    p = (sv > -1e29f) ? p : 0.f;   // robust under full-mask + defer
                    psum[i][r] += p;
                    Ps[qbase + i * 16 + r4 + r][col] = (bf16)p;
                }
            }
        }
        #pragma unroll
        for (int off = 8; off >= 1; off >>= 1)
            #pragma unroll
            for (int i = 0; i < 2; i++)
                #pragma unroll
                for (int r = 0; r < 4; r++) psum[i][r] += __shfl_xor(psum[i][r], off);
        #pragma unroll
        for (int i = 0; i < 2; i++)
            #pragma unroll
            for (int r = 0; r < 4; r++) lrow[i][r] += psum[i][r];

        __syncthreads();   // Ps writes before reads

        // O += P V
        #pragma unroll
        for (int ks = 0; ks < 2; ks++) {
            bf16x8 vfr[4];
            #pragma unroll
            for (int nt = 0; nt < 4; nt++)
                vfr[nt] = *reinterpret_cast<const bf16x8*>(&Vs[16 * nt + m16][32 * ks + koff]);
            #pragma unroll
            for (int i = 0; i < 2; i++) {
                bf16x8 pf = *reinterpret_cast<const bf16x8*>(&Ps[qbase + i * 16 + m16][32 * ks + koff]);
                #pragma unroll
                for (int nt = 0; nt < 4; nt++)
                    o_acc[i][nt] = __builtin_amdgcn_mfma_f32_16x16x32_bf16(pf, vfr[nt], o_acc[i][nt], 0, 0, 0);
            }
        }
        __syncthreads();   // protect Ks/Vs/Ps
    }

    // epilogue: O /= l, store bf16
    #pragma unroll
    for (int i = 0; i < 2; i++) {
        #pragma unroll
        for (int r = 0; r < 4; r++) {
            float invl = 1.f / lrow[i][r];
            int q = qt * 128 + qbase + i * 16 + r4 + r;
            #pragma unroll
            for (int nt = 0; nt < 4; nt++)
                ob[(size_t)(t0 + q) * C + n * HD + m16 + 16 * nt] = (bf16)(o_acc[i][nt][r] * invl);
        }
    }
}

// ---------------------------------------------------------------- launch
extern "C" void kernel_launch(void* const* d_in, const int* in_sizes, int n_in,
                              void* d_out, int out_size, void* d_ws, size_t ws_size,
                              hipStream_t stream) {
    const int*   idx    = (const int*)  d_in[0];
    const float* tok    = (const float*)d_in[1];
    const float* pos    = (const float*)d_in[2];
    const float* wk     = (const float*)d_in[3];
    const float* wq     = (const float*)d_in[4];
    const float* wv     = (const float*)d_in[5];
    const float* w_proj = (const float*)d_in[6];
    const float* w_in   = (const float*)d_in[7];
    const float* w_out  = (const float*)d_in[8];
    float* out = (float*)d_out;

    // Workspace layout: exactly 88 MiB (the proven-safe footprint).
    //   xf 16 | xb 8 | [wqkvT 6 | wpT 2 | w_inT 8 | w_outT 8 | kvq 24 | vt 8 | obuf 8]
    // tokT (62.5 MiB, live only for logits) aliases the bracketed 64 MiB region.
    // hbuf (32 MiB, live FFN-in -> FFN-out) lives in d_out (dead until logits).
    char* w = (char*)d_ws;
    float* xf     = (float*)w;   w += (size_t)TOK * C * 4;    // 16 MiB f32 master
    bf16* xb      = (bf16*)w;    w += (size_t)TOK * C * 2;    //  8 MiB
    char* alias0  = w;
    bf16* wqkvT   = (bf16*)w;    w += (size_t)3 * C * C * 2;  //  6 MiB (rows: k|v|q per quirk)
    bf16* wpT     = (bf16*)w;    w += (size_t)C * C * 2;      //  2 MiB
    bf16* w_inT   = (bf16*)w;    w += (size_t)C * FF * 2;     //  8 MiB
    bf16* w_outT  = (bf16*)w;    w += (size_t)C * FF * 2;     //  8 MiB
    bf16* kvq     = (bf16*)w;    w += (size_t)TOK * 3 * C * 2;// 24 MiB
    bf16* vt      = (bf16*)w;    w += (size_t)TOK * C * 2;    //  8 MiB
    bf16* obuf    = (bf16*)w;    w += (size_t)TOK * C * 2;    //  8 MiB
    bf16* tokT = (bf16*)alias0;          // needs 62.5 MiB <= 64 MiB region
    bf16* hbuf = (bf16*)d_out;           // 32 MiB of the 500 MiB output buffer

    embed_kernel<<<TOK * C / 256, 256, 0, stream>>>(idx, tok, pos, xf, xb);

    // weight prep (once): transpose KxN f32 -> NxK bf16; convert NxK f32 -> bf16
    wtrans_kernel<<<dim3(C / 64, C / 64), 256, 0, stream>>>(wk, wqkvT, C, C);
    wtrans_kernel<<<dim3(C / 64, C / 64), 256, 0, stream>>>(wq, wqkvT + (size_t)C * C, C, C);
    wtrans_kernel<<<dim3(C / 64, C / 64), 256, 0, stream>>>(wv, wqkvT + (size_t)2 * C * C, C, C);
    wtrans_kernel<<<dim3(FF / 64, C / 64), 256, 0, stream>>>(w_in, w_inT, C, FF);
    wtrans_kernel<<<dim3(C / 64, FF / 64), 256, 0, stream>>>(w_out, w_outT, FF, C);
    wconv_kernel<<<C * C / 2048, 256, 0, stream>>>(w_proj, wpT);   // already NxK

    dim3 gQKV(3 * C / 128, TOK / 128);   // (24, 32)  768 wgs
    dim3 gCn(C / 64, TOK / 128);         // (16, 32)  512 wgs (NT=2 -> BN=64)
    dim3 gF(FF / 128, TOK / 128);        // (32, 32)  1024 wgs
    dim3 gV(VOC / 128, TOK / 128);       // (250, 32) 8000 wgs

    for (int layer = 0; layer < 4; layer++) {
        // fused QKV: cols 0..C-1 = x@wk (k), C..2C-1 = x@wq (v), 2C..3C-1 = x@wv (q)
        gemm128_kernel<0, 4><<<gQKV, 256, 0, stream>>>(xb, wqkvT, kvq, nullptr, nullptr, TOK, 3 * C, C);

        vtrans_kernel<<<dim3(TT / 64, NH, 4), 256, 0, stream>>>(kvq + C, vt, 3 * C);
        fattn_kernel<<<dim3(TT / 128, NH, 4), 256, 0, stream>>>(kvq + 2 * C, kvq, vt, obuf, 3 * C);

        // x += o @ w_proj^T
        gemm128_kernel<2, 2><<<gCn, 256, 0, stream>>>(obuf, wpT, xb, nullptr, xf, TOK, C, C);
        // h = relu(x @ w_in)
        gemm128_kernel<1, 4><<<gF, 256, 0, stream>>>(xb, w_inT, hbuf, nullptr, nullptr, TOK, FF, C);
        // x += h @ w_out
        gemm128_kernel<2, 2><<<gCn, 256, 0, stream>>>(hbuf, w_outT, xb, nullptr, xf, TOK, C, FF);
    }

    // logits = x @ token_emb^T (tokT bf16 NxK), f32 out (nontemporal stores)
    wconv_kernel<<<VOC * C / 2048, 256, 0, stream>>>(tok, tokT);
    gemm128_kernel<3, 4><<<gV, 256, 0, stream>>>(xb, tokT, nullptr, out, nullptr, TOK, VOC, C);
}